// Round 3
// baseline (865.028 us; speedup 1.0000x reference)
//
#include <hip/hip_runtime.h>

#define NN 100000
#define EE 1600000
#define TT 32
#define DEMB 96
#define DH 128
#define DMLP 256
#define BB 64
#define EDGE_CAP (EE + 8 * NN)

// ---------------- init ----------------
__global__ __launch_bounds__(256) void k_init(int* cnt, int* conn, float* sums, float* cntB, int* total, int n) {
    int i = blockIdx.x * 256 + threadIdx.x;
    if (i < n) { cnt[i] = 0; conn[i] = 0; }
    if (i < BB * DH) sums[i] = 0.f;
    if (i < BB) cntB[i] = 0.f;
    if (i == 0) *total = 0;
}

// ---------------- degree count + connected mask ----------------
__global__ __launch_bounds__(256) void k_count(const int* __restrict__ row, const int* __restrict__ col,
                                               int* cnt, int* conn, int e) {
    int i = blockIdx.x * 256 + threadIdx.x;
    if (i >= e) return;
    int r = row[i], c = col[i];
    atomicAdd(&cnt[c], 1);
    conn[r] = 1;
    conn[c] = 1;
}

// ---------------- offset allocation (8-aligned segments) + node props + pad fill ----------
__global__ __launch_bounds__(256) void k_alloc(const int* __restrict__ cnt, const int* __restrict__ x,
                                               int* off, int* cursor, float* dinv, int2* nodeP,
                                               int2* edges, int* total, int n) {
    int i = blockIdx.x * 256 + threadIdx.x;
    int lane = threadIdx.x & 63;
    int c = (i < n) ? cnt[i] : 0;
    int pad = (c + 7) & ~7;  // segment rounded to 8 -> int4-aligned, tail-free unroll
    int s = pad;
#pragma unroll
    for (int d = 1; d < 64; d <<= 1) { int t = __shfl_up(s, d); if (lane >= d) s += t; }
    int tot = __shfl(s, 63);
    int base = 0;
    if (lane == 63) base = atomicAdd(total, tot);
    base = __shfl(base, 63);
    int o = base + s - pad;  // exclusive prefix + wave base
    if (i < n) {
        off[i] = o;
        cursor[i] = o;
        float di = 1.0f / sqrtf((float)(1 + c));  // self-loop included
        dinv[i] = di;
        nodeP[i] = make_int2(x[i], __float_as_int(di));
        for (int j = c; j < pad; j++) edges[o + j] = make_int2(0, 0);  // zero-weight padding
    }
}

// ---------------- scatter edges into CSR (by destination), packed (src|type<<20, w) -------
__global__ __launch_bounds__(256) void k_fill(const int* __restrict__ row, const int* __restrict__ col,
                                              int* cursor, int2* edges, const int2* __restrict__ nodeP, int e) {
    int i = blockIdx.x * 256 + threadIdx.x;
    if (i >= e) return;
    int r = row[i], c = col[i];
    int2 pr = nodeP[r];
    int2 pc = nodeP[c];
    float w = __int_as_float(pr.y) * __int_as_float(pc.y);
    int pos = atomicAdd(&cursor[c], 1);
    edges[pos] = make_int2(r | (pr.x << 20), __float_as_int(w));
}

// ---------------- layer-0 tables: Tm = emb@W0, Tp = emb@P0 + pb0 ----------------
__global__ __launch_bounds__(128) void k_tables(const float* __restrict__ emb, const float* __restrict__ W0,
                                                const float* __restrict__ P0, const float* __restrict__ pb0,
                                                float* Tm, float* Tp) {
    int t = blockIdx.x;      // 0..31
    int j = threadIdx.x;     // 0..127
    float am = 0.f, ap = 0.f;
    for (int k = 0; k < DEMB; k++) {
        float ev = emb[t * DEMB + k];
        am += ev * W0[k * DH + j];
        ap += ev * P0[k * DH + j];
    }
    Tm[t * DH + j] = am;
    Tp[t * DH + j] = ap + pb0[j];
}

// ---------------- layer-0 aggregation: per-edge LDS table lookup (type packed in edge) ----
__global__ __launch_bounds__(256) void k_agg0(float* __restrict__ H, const int2* __restrict__ edges,
                                              const int* __restrict__ off, const int* __restrict__ cnt,
                                              const float* __restrict__ dinv, const float* __restrict__ b0,
                                              const int* __restrict__ x,
                                              const float* __restrict__ Tm, const float* __restrict__ Tp, int n) {
    __shared__ float sTm[TT * DH];
    __shared__ float sTp[TT * DH];
    int tid = threadIdx.x;
    for (int i2 = 0; i2 < 4; i2++) {
        int f = tid + i2 * 256;  // float4 index over 1024
        ((float4*)sTm)[f] = ((const float4*)Tm)[f];
        ((float4*)sTp)[f] = ((const float4*)Tp)[f];
    }
    __syncthreads();
    int wid = tid >> 6, lane = tid & 63;
    int node = blockIdx.x * 4 + wid;
    if (node >= n) return;
    int beg = off[node], num = cnt[node];
    int fo = lane * 2;
    float a0 = 0.f, a1 = 0.f;
    for (int i = 0; i < num; i += 8) {
        int4 e01 = *((const int4*)&edges[beg + i]);
        int4 e23 = *((const int4*)&edges[beg + i + 2]);
        int4 e45 = *((const int4*)&edges[beg + i + 4]);
        int4 e67 = *((const int4*)&edges[beg + i + 6]);
#define P0E(si, wi)                                            \
        {                                                      \
            int t = (si) >> 20;                                \
            float w = __int_as_float(wi);                      \
            float2 v = *((const float2*)&sTm[t * DH + fo]);    \
            a0 += w * v.x;                                     \
            a1 += w * v.y;                                     \
        }
        P0E(e01.x, e01.y) P0E(e01.z, e01.w)
        P0E(e23.x, e23.y) P0E(e23.z, e23.w)
        P0E(e45.x, e45.y) P0E(e45.z, e45.w)
        P0E(e67.x, e67.y) P0E(e67.z, e67.w)
#undef P0E
    }
    int xn = x[node];
    float di = dinv[node];
    float wl = di * di;
    float2 vs = *((const float2*)&sTm[xn * DH + fo]);
    a0 += wl * vs.x;
    a1 += wl * vs.y;
    float2 bb = *((const float2*)&b0[fo]);
    a0 += bb.x;
    a1 += bb.y;
    float2 pp = *((const float2*)&sTp[xn * DH + fo]);
    float r0 = 0.5f * pp.x + 0.5f * a0;
    float r1 = 0.5f * pp.y + 0.5f * a1;
    r0 = fmaxf(r0, 0.f);
    r1 = fmaxf(r1, 0.f);
    *((float2*)&H[(size_t)node * DH + fo]) = make_float2(r0, r1);
}

// ---------------- layers 1/2 aggregation (in-place on H, 8 gathers in flight) -------------
template <int RELU>
__global__ __launch_bounds__(256) void k_agg(const float* __restrict__ M, float* __restrict__ H,
                                             const int2* __restrict__ edges,
                                             const int* __restrict__ off, const int* __restrict__ cnt,
                                             const float* __restrict__ dinv, const float* __restrict__ bias, int n) {
    int wid = threadIdx.x >> 6, lane = threadIdx.x & 63;
    int node = blockIdx.x * 4 + wid;
    if (node >= n) return;
    int beg = off[node], num = cnt[node];
    int fo = lane * 2;
    float a0 = 0.f, a1 = 0.f;
    for (int i = 0; i < num; i += 8) {
        int4 e01 = *((const int4*)&edges[beg + i]);
        int4 e23 = *((const int4*)&edges[beg + i + 2]);
        int4 e45 = *((const int4*)&edges[beg + i + 4]);
        int4 e67 = *((const int4*)&edges[beg + i + 6]);
        int s0 = e01.x & 0xFFFFF, s1 = e01.z & 0xFFFFF;
        int s2 = e23.x & 0xFFFFF, s3 = e23.z & 0xFFFFF;
        int s4 = e45.x & 0xFFFFF, s5 = e45.z & 0xFFFFF;
        int s6 = e67.x & 0xFFFFF, s7 = e67.z & 0xFFFFF;
        float2 v0 = *((const float2*)&M[(size_t)s0 * DH + fo]);
        float2 v1 = *((const float2*)&M[(size_t)s1 * DH + fo]);
        float2 v2 = *((const float2*)&M[(size_t)s2 * DH + fo]);
        float2 v3 = *((const float2*)&M[(size_t)s3 * DH + fo]);
        float2 v4 = *((const float2*)&M[(size_t)s4 * DH + fo]);
        float2 v5 = *((const float2*)&M[(size_t)s5 * DH + fo]);
        float2 v6 = *((const float2*)&M[(size_t)s6 * DH + fo]);
        float2 v7 = *((const float2*)&M[(size_t)s7 * DH + fo]);
        float w0 = __int_as_float(e01.y), w1 = __int_as_float(e01.w);
        float w2 = __int_as_float(e23.y), w3 = __int_as_float(e23.w);
        float w4 = __int_as_float(e45.y), w5 = __int_as_float(e45.w);
        float w6 = __int_as_float(e67.y), w7 = __int_as_float(e67.w);
        a0 += w0 * v0.x; a1 += w0 * v0.y;
        a0 += w1 * v1.x; a1 += w1 * v1.y;
        a0 += w2 * v2.x; a1 += w2 * v2.y;
        a0 += w3 * v3.x; a1 += w3 * v3.y;
        a0 += w4 * v4.x; a1 += w4 * v4.y;
        a0 += w5 * v5.x; a1 += w5 * v5.y;
        a0 += w6 * v6.x; a1 += w6 * v6.y;
        a0 += w7 * v7.x; a1 += w7 * v7.y;
    }
    float di = dinv[node];
    float wl = di * di;
    float2 vc = *((const float2*)&M[(size_t)node * DH + fo]);
    a0 += wl * vc.x;
    a1 += wl * vc.y;
    float2 bb = *((const float2*)&bias[fo]);
    a0 += bb.x;
    a1 += bb.y;
    size_t hb = (size_t)node * DH + fo;
    float2 h = *((float2*)&H[hb]);
    float r0 = 0.5f * h.x + 0.5f * a0;
    float r1 = 0.5f * h.y + 0.5f * a1;
    if (RELU) { r0 = fmaxf(r0, 0.f); r1 = fmaxf(r1, 0.f); }
    *((float2*)&H[hb]) = make_float2(r0, r1);
}

// ---------------- fp32 GEMM: C[n x 128] = A[n x 128] @ W[128 x 128] ----------------
__global__ __launch_bounds__(256) void k_gemm(const float* __restrict__ A, const float* __restrict__ W,
                                              float* __restrict__ C, int n) {
    __shared__ float sA[128 * 132];  // padded stride 132
    __shared__ float sW[128 * 128];
    int tid = threadIdx.x;
    int base = blockIdx.x * 128;
    for (int i = 0; i < 16; i++) {
        int f = tid + i * 256;
        ((float4*)sW)[f] = ((const float4*)W)[f];
    }
    for (int i = 0; i < 16; i++) {
        int f = tid + i * 256;    // float4 idx, 32 per row
        int r = f >> 5, c4 = f & 31;
        int gr = base + r;
        float4 v = make_float4(0.f, 0.f, 0.f, 0.f);
        if (gr < n) v = *((const float4*)&A[(size_t)gr * DH + c4 * 4]);
        *((float4*)&sA[r * 132 + c4 * 4]) = v;
    }
    __syncthreads();
    int ty = tid >> 4, tx = tid & 15;
    int r0 = ty * 8, c0 = tx * 8;
    float acc[8][8];
#pragma unroll
    for (int i = 0; i < 8; i++)
#pragma unroll
        for (int j = 0; j < 8; j++) acc[i][j] = 0.f;

    for (int k = 0; k < 128; k += 4) {
        float4 a[8];
        float4 b[8];
#pragma unroll
        for (int i = 0; i < 8; i++) a[i] = *((float4*)&sA[(r0 + i) * 132 + k]);
#pragma unroll
        for (int kk = 0; kk < 4; kk++) {
            b[kk * 2]     = *((float4*)&sW[(k + kk) * 128 + c0]);
            b[kk * 2 + 1] = *((float4*)&sW[(k + kk) * 128 + c0 + 4]);
        }
#pragma unroll
        for (int i = 0; i < 8; i++) {
            float av[4] = {a[i].x, a[i].y, a[i].z, a[i].w};
#pragma unroll
            for (int kk = 0; kk < 4; kk++) {
                float4 b0v = b[kk * 2], b1v = b[kk * 2 + 1];
                acc[i][0] += av[kk] * b0v.x;
                acc[i][1] += av[kk] * b0v.y;
                acc[i][2] += av[kk] * b0v.z;
                acc[i][3] += av[kk] * b0v.w;
                acc[i][4] += av[kk] * b1v.x;
                acc[i][5] += av[kk] * b1v.y;
                acc[i][6] += av[kk] * b1v.z;
                acc[i][7] += av[kk] * b1v.w;
            }
        }
    }
#pragma unroll
    for (int i = 0; i < 8; i++) {
        int gr = base + r0 + i;
        if (gr < n) {
            float4 v0 = make_float4(acc[i][0], acc[i][1], acc[i][2], acc[i][3]);
            float4 v1 = make_float4(acc[i][4], acc[i][5], acc[i][6], acc[i][7]);
            *((float4*)&C[(size_t)gr * DH + c0]) = v0;
            *((float4*)&C[(size_t)gr * DH + c0 + 4]) = v1;
        }
    }
}

// ---------------- pooling ----------------
__device__ inline int lbound(const int* a, int n, int v) {
    int lo = 0, hi = n;
    while (lo < hi) {
        int mid = (lo + hi) >> 1;
        if (a[mid] < v) lo = mid + 1; else hi = mid;
    }
    return lo;
}

__global__ __launch_bounds__(128) void k_pool(const float* __restrict__ H, const int* __restrict__ conn,
                                              const int* __restrict__ batch, float* sums, float* cntB, int n) {
    int b = blockIdx.x >> 3;
    int s = blockIdx.x & 7;
    int start = lbound(batch, n, b);
    int end = lbound(batch, n, b + 1);
    int d = threadIdx.x;
    float acc = 0.f, c = 0.f;
    for (int i = start + s; i < end; i += 8) {
        if (conn[i]) {
            acc += H[(size_t)i * DH + d];
            c += 1.f;
        }
    }
    atomicAdd(&sums[b * DH + d], acc);
    if (d == 0) atomicAdd(&cntB[b], c);
}

// ---------------- MLP head ----------------
__global__ __launch_bounds__(256) void k_mlp(const float* __restrict__ sums, const float* __restrict__ cntB,
                                             const float* __restrict__ M1, const float* __restrict__ mb1,
                                             const float* __restrict__ M2, const float* __restrict__ mb2,
                                             float* out) {
    int b = blockIdx.x;
    int j = threadIdx.x;
    __shared__ float g[DH];
    __shared__ float red[DMLP];
    float inv = 1.0f / fmaxf(cntB[b], 1.0f);
    if (j < DH) g[j] = sums[b * DH + j] * inv;
    __syncthreads();
    float acc = mb1[j];
    for (int k = 0; k < DH; k++) acc += g[k] * M1[k * DMLP + j];
    float v = fmaxf(acc, 0.f) * M2[j];
    red[j] = v;
    __syncthreads();
    for (int sdiv = 128; sdiv > 0; sdiv >>= 1) {
        if (j < sdiv) red[j] += red[j + sdiv];
        __syncthreads();
    }
    if (j == 0) out[b] = red[0] + mb2[0];
}

// ---------------- launch ----------------
extern "C" void kernel_launch(void* const* d_in, const int* in_sizes, int n_in,
                              void* d_out, int out_size, void* d_ws, size_t ws_size,
                              hipStream_t stream) {
    const int* x      = (const int*)d_in[0];
    const int* ei     = (const int*)d_in[1];
    const int* batch  = (const int*)d_in[2];
    const float* emb  = (const float*)d_in[3];
    const float* W0   = (const float*)d_in[4];
    const float* b0   = (const float*)d_in[5];
    const float* W1   = (const float*)d_in[6];
    const float* b1   = (const float*)d_in[7];
    const float* W2   = (const float*)d_in[8];
    const float* b2   = (const float*)d_in[9];
    const float* P0   = (const float*)d_in[10];
    const float* pb0  = (const float*)d_in[11];
    const float* M1   = (const float*)d_in[12];
    const float* mb1  = (const float*)d_in[13];
    const float* M2   = (const float*)d_in[14];
    const float* mb2  = (const float*)d_in[15];
    float* out = (float*)d_out;

    const int* row = ei;
    const int* col = ei + EE;

    char* p = (char*)d_ws;
    auto alloc = [&](size_t bytes) {
        void* q = (void*)p;
        p += (bytes + 255) & ~(size_t)255;
        return q;
    };
    int* cnt      = (int*)alloc(NN * 4);
    int* off      = (int*)alloc(NN * 4);
    int* cursor   = (int*)alloc(NN * 4);
    int* conn     = (int*)alloc(NN * 4);
    float* dinv   = (float*)alloc(NN * 4);
    int2* nodeP   = (int2*)alloc((size_t)NN * 8);
    int* total    = (int*)alloc(256);
    int2* edges   = (int2*)alloc((size_t)EDGE_CAP * 8);
    float* Tm     = (float*)alloc(TT * DH * 4);
    float* Tp     = (float*)alloc(TT * DH * 4);
    float* H      = (float*)alloc((size_t)NN * DH * 4);
    float* M      = (float*)alloc((size_t)NN * DH * 4);
    float* sums   = (float*)alloc(BB * DH * 4);
    float* cntB   = (float*)alloc(BB * 4);

    int gN = (NN + 255) / 256;
    int gE = (EE + 255) / 256;

    k_init<<<gN, 256, 0, stream>>>(cnt, conn, sums, cntB, total, NN);
    k_count<<<gE, 256, 0, stream>>>(row, col, cnt, conn, EE);
    k_alloc<<<gN, 256, 0, stream>>>(cnt, x, off, cursor, dinv, nodeP, edges, total, NN);
    k_fill<<<gE, 256, 0, stream>>>(row, col, cursor, edges, nodeP, EE);
    k_tables<<<TT, 128, 0, stream>>>(emb, W0, P0, pb0, Tm, Tp);
    k_agg0<<<(NN + 3) / 4, 256, 0, stream>>>(H, edges, off, cnt, dinv, b0, x, Tm, Tp, NN);
    k_gemm<<<(NN + 127) / 128, 256, 0, stream>>>(H, W1, M, NN);
    k_agg<1><<<(NN + 3) / 4, 256, 0, stream>>>(M, H, edges, off, cnt, dinv, b1, NN);
    k_gemm<<<(NN + 127) / 128, 256, 0, stream>>>(H, W2, M, NN);
    k_agg<0><<<(NN + 3) / 4, 256, 0, stream>>>(M, H, edges, off, cnt, dinv, b2, NN);
    k_pool<<<BB * 8, 128, 0, stream>>>(H, conn, batch, sums, cntB, NN);
    k_mlp<<<BB, 256, 0, stream>>>(sums, cntB, M1, mb1, M2, mb2, out);
}

// Round 4
// 810.397 us; speedup vs baseline: 1.0674x; 1.0674x over previous
//
#include <hip/hip_runtime.h>

#define NN 100000
#define EE 1600000
#define TT 32
#define DEMB 96
#define DH 128
#define DMLP 256
#define BB 64
#define EDGE_CAP (EE + 8 * NN)

// ---------------- init ----------------
__global__ __launch_bounds__(256) void k_init(int* cnt, int* conn, float* sums, float* cntB, int* total, int n) {
    int i = blockIdx.x * 256 + threadIdx.x;
    if (i < n) { cnt[i] = 0; conn[i] = 0; }
    if (i < BB * DH) sums[i] = 0.f;
    if (i < BB) cntB[i] = 0.f;
    if (i == 0) *total = 0;
}

// ---------------- degree count + connected mask ----------------
__global__ __launch_bounds__(256) void k_count(const int* __restrict__ row, const int* __restrict__ col,
                                               int* cnt, int* conn, int e) {
    int i = blockIdx.x * 256 + threadIdx.x;
    if (i >= e) return;
    int r = row[i], c = col[i];
    atomicAdd(&cnt[c], 1);
    conn[r] = 1;
    conn[c] = 1;
}

// ---------------- offset allocation (8-aligned segments) + node props + pad fill ----------
__global__ __launch_bounds__(256) void k_alloc(const int* __restrict__ cnt, const int* __restrict__ x,
                                               int* off, int* cursor, float* dinv, int2* nodeP,
                                               int2* edges, int* total, int n) {
    int i = blockIdx.x * 256 + threadIdx.x;
    int lane = threadIdx.x & 63;
    int c = (i < n) ? cnt[i] : 0;
    int pad = (c + 7) & ~7;  // segment rounded to 8 -> int4-aligned, tail-free unroll
    int s = pad;
#pragma unroll
    for (int d = 1; d < 64; d <<= 1) { int t = __shfl_up(s, d); if (lane >= d) s += t; }
    int tot = __shfl(s, 63);
    int base = 0;
    if (lane == 63) base = atomicAdd(total, tot);
    base = __shfl(base, 63);
    int o = base + s - pad;  // exclusive prefix + wave base
    if (i < n) {
        off[i] = o;
        cursor[i] = o;
        float di = 1.0f / sqrtf((float)(1 + c));  // self-loop included
        dinv[i] = di;
        nodeP[i] = make_int2(x[i], __float_as_int(di));
        for (int j = c; j < pad; j++) edges[o + j] = make_int2(0, 0);  // zero-weight padding
    }
}

// ---------------- scatter edges into CSR (by destination), packed (src|type<<20, w) -------
__global__ __launch_bounds__(256) void k_fill(const int* __restrict__ row, const int* __restrict__ col,
                                              int* cursor, int2* edges, const int2* __restrict__ nodeP, int e) {
    int i = blockIdx.x * 256 + threadIdx.x;
    if (i >= e) return;
    int r = row[i], c = col[i];
    int2 pr = nodeP[r];
    int2 pc = nodeP[c];
    float w = __int_as_float(pr.y) * __int_as_float(pc.y);
    int pos = atomicAdd(&cursor[c], 1);
    edges[pos] = make_int2(r | (pr.x << 20), __float_as_int(w));
}

// ---------------- layer-0 tables: Tm = emb@W0, Tp = emb@P0 + pb0 ----------------
__global__ __launch_bounds__(128) void k_tables(const float* __restrict__ emb, const float* __restrict__ W0,
                                                const float* __restrict__ P0, const float* __restrict__ pb0,
                                                float* Tm, float* Tp) {
    int t = blockIdx.x;      // 0..31
    int j = threadIdx.x;     // 0..127
    float am = 0.f, ap = 0.f;
    for (int k = 0; k < DEMB; k++) {
        float ev = emb[t * DEMB + k];
        am += ev * W0[k * DH + j];
        ap += ev * P0[k * DH + j];
    }
    Tm[t * DH + j] = am;
    Tp[t * DH + j] = ap + pb0[j];
}

// ---------------- layer-0 aggregation: 2 nodes/wave, float4/lane, LDS table lookups -------
__global__ __launch_bounds__(256) void k_agg0(float* __restrict__ H, const int2* __restrict__ edges,
                                              const int* __restrict__ off, const int* __restrict__ cnt,
                                              const float* __restrict__ dinv, const float* __restrict__ b0,
                                              const int* __restrict__ x,
                                              const float* __restrict__ Tm, const float* __restrict__ Tp, int n) {
    __shared__ float sTm[TT * DH];
    __shared__ float sTp[TT * DH];
    int tid = threadIdx.x;
    for (int i2 = 0; i2 < 4; i2++) {
        int f = tid + i2 * 256;  // float4 index over 1024
        ((float4*)sTm)[f] = ((const float4*)Tm)[f];
        ((float4*)sTp)[f] = ((const float4*)Tp)[f];
    }
    __syncthreads();
    int wid = tid >> 6, lane = tid & 63;
    int half = lane >> 5, sub = lane & 31;
    int node = blockIdx.x * 8 + wid * 2 + half;
    if (node >= n) return;
    int beg = off[node], num = cnt[node];
    int fo = sub * 4;
    float a0 = 0.f, a1 = 0.f, a2 = 0.f, a3 = 0.f;
    for (int i = 0; i < num; i += 8) {
        int4 e01 = *((const int4*)&edges[beg + i]);
        int4 e23 = *((const int4*)&edges[beg + i + 2]);
        int4 e45 = *((const int4*)&edges[beg + i + 4]);
        int4 e67 = *((const int4*)&edges[beg + i + 6]);
#define P0E(si, wi)                                            \
        {                                                      \
            int t = (si) >> 20;                                \
            float w = __int_as_float(wi);                      \
            float4 v = *((const float4*)&sTm[t * DH + fo]);    \
            a0 += w * v.x; a1 += w * v.y;                      \
            a2 += w * v.z; a3 += w * v.w;                      \
        }
        P0E(e01.x, e01.y) P0E(e01.z, e01.w)
        P0E(e23.x, e23.y) P0E(e23.z, e23.w)
        P0E(e45.x, e45.y) P0E(e45.z, e45.w)
        P0E(e67.x, e67.y) P0E(e67.z, e67.w)
#undef P0E
    }
    int xn = x[node];
    float di = dinv[node];
    float wl = di * di;
    float4 vs = *((const float4*)&sTm[xn * DH + fo]);
    a0 += wl * vs.x; a1 += wl * vs.y; a2 += wl * vs.z; a3 += wl * vs.w;
    float4 bb = *((const float4*)&b0[fo]);
    a0 += bb.x; a1 += bb.y; a2 += bb.z; a3 += bb.w;
    float4 pp = *((const float4*)&sTp[xn * DH + fo]);
    float4 r;
    r.x = fmaxf(0.5f * pp.x + 0.5f * a0, 0.f);
    r.y = fmaxf(0.5f * pp.y + 0.5f * a1, 0.f);
    r.z = fmaxf(0.5f * pp.z + 0.5f * a2, 0.f);
    r.w = fmaxf(0.5f * pp.w + 0.5f * a3, 0.f);
    *((float4*)&H[(size_t)node * DH + fo]) = r;
}

// ---------------- layers 1/2 aggregation: 2 nodes/wave, float4/lane, 8 gathers deep -------
template <int RELU>
__global__ __launch_bounds__(256) void k_agg(const float* __restrict__ M, float* __restrict__ H,
                                             const int2* __restrict__ edges,
                                             const int* __restrict__ off, const int* __restrict__ cnt,
                                             const float* __restrict__ dinv, const float* __restrict__ bias, int n) {
    int tid = threadIdx.x;
    int wid = tid >> 6, lane = tid & 63;
    int half = lane >> 5, sub = lane & 31;
    int node = blockIdx.x * 8 + wid * 2 + half;
    if (node >= n) return;
    int beg = off[node], num = cnt[node];
    int fo = sub * 4;
    size_t hb = (size_t)node * DH + fo;
    // hoisted loads (independent of edge loop)
    float4 h = *((const float4*)&H[hb]);
    float4 vc = *((const float4*)&M[hb]);
    float4 bb = *((const float4*)&bias[fo]);
    float di = dinv[node];
    float a0 = 0.f, a1 = 0.f, a2 = 0.f, a3 = 0.f;
    for (int i = 0; i < num; i += 8) {
        int4 e01 = *((const int4*)&edges[beg + i]);
        int4 e23 = *((const int4*)&edges[beg + i + 2]);
        int4 e45 = *((const int4*)&edges[beg + i + 4]);
        int4 e67 = *((const int4*)&edges[beg + i + 6]);
        float4 v0 = *((const float4*)&M[(size_t)(e01.x & 0xFFFFF) * DH + fo]);
        float4 v1 = *((const float4*)&M[(size_t)(e01.z & 0xFFFFF) * DH + fo]);
        float4 v2 = *((const float4*)&M[(size_t)(e23.x & 0xFFFFF) * DH + fo]);
        float4 v3 = *((const float4*)&M[(size_t)(e23.z & 0xFFFFF) * DH + fo]);
        float4 v4 = *((const float4*)&M[(size_t)(e45.x & 0xFFFFF) * DH + fo]);
        float4 v5 = *((const float4*)&M[(size_t)(e45.z & 0xFFFFF) * DH + fo]);
        float4 v6 = *((const float4*)&M[(size_t)(e67.x & 0xFFFFF) * DH + fo]);
        float4 v7 = *((const float4*)&M[(size_t)(e67.z & 0xFFFFF) * DH + fo]);
        float w0 = __int_as_float(e01.y), w1 = __int_as_float(e01.w);
        float w2 = __int_as_float(e23.y), w3 = __int_as_float(e23.w);
        float w4 = __int_as_float(e45.y), w5 = __int_as_float(e45.w);
        float w6 = __int_as_float(e67.y), w7 = __int_as_float(e67.w);
        a0 += w0 * v0.x; a1 += w0 * v0.y; a2 += w0 * v0.z; a3 += w0 * v0.w;
        a0 += w1 * v1.x; a1 += w1 * v1.y; a2 += w1 * v1.z; a3 += w1 * v1.w;
        a0 += w2 * v2.x; a1 += w2 * v2.y; a2 += w2 * v2.z; a3 += w2 * v2.w;
        a0 += w3 * v3.x; a1 += w3 * v3.y; a2 += w3 * v3.z; a3 += w3 * v3.w;
        a0 += w4 * v4.x; a1 += w4 * v4.y; a2 += w4 * v4.z; a3 += w4 * v4.w;
        a0 += w5 * v5.x; a1 += w5 * v5.y; a2 += w5 * v5.z; a3 += w5 * v5.w;
        a0 += w6 * v6.x; a1 += w6 * v6.y; a2 += w6 * v6.z; a3 += w6 * v6.w;
        a0 += w7 * v7.x; a1 += w7 * v7.y; a2 += w7 * v7.z; a3 += w7 * v7.w;
    }
    float wl = di * di;
    a0 += wl * vc.x; a1 += wl * vc.y; a2 += wl * vc.z; a3 += wl * vc.w;
    a0 += bb.x; a1 += bb.y; a2 += bb.z; a3 += bb.w;
    float4 r;
    r.x = 0.5f * h.x + 0.5f * a0;
    r.y = 0.5f * h.y + 0.5f * a1;
    r.z = 0.5f * h.z + 0.5f * a2;
    r.w = 0.5f * h.w + 0.5f * a3;
    if (RELU) {
        r.x = fmaxf(r.x, 0.f); r.y = fmaxf(r.y, 0.f);
        r.z = fmaxf(r.z, 0.f); r.w = fmaxf(r.w, 0.f);
    }
    *((float4*)&H[hb]) = r;
}

// ---------------- fp32 GEMM: C[n x 128] = A[n x 128] @ W[128 x 128] ----------------
__global__ __launch_bounds__(256) void k_gemm(const float* __restrict__ A, const float* __restrict__ W,
                                              float* __restrict__ C, int n) {
    __shared__ float sA[128 * 132];  // padded stride 132
    __shared__ float sW[128 * 128];
    int tid = threadIdx.x;
    int base = blockIdx.x * 128;
    for (int i = 0; i < 16; i++) {
        int f = tid + i * 256;
        ((float4*)sW)[f] = ((const float4*)W)[f];
    }
    for (int i = 0; i < 16; i++) {
        int f = tid + i * 256;    // float4 idx, 32 per row
        int r = f >> 5, c4 = f & 31;
        int gr = base + r;
        float4 v = make_float4(0.f, 0.f, 0.f, 0.f);
        if (gr < n) v = *((const float4*)&A[(size_t)gr * DH + c4 * 4]);
        *((float4*)&sA[r * 132 + c4 * 4]) = v;
    }
    __syncthreads();
    int ty = tid >> 4, tx = tid & 15;
    int r0 = ty * 8, c0 = tx * 8;
    float acc[8][8];
#pragma unroll
    for (int i = 0; i < 8; i++)
#pragma unroll
        for (int j = 0; j < 8; j++) acc[i][j] = 0.f;

    for (int k = 0; k < 128; k += 4) {
        float4 a[8];
        float4 b[8];
#pragma unroll
        for (int i = 0; i < 8; i++) a[i] = *((float4*)&sA[(r0 + i) * 132 + k]);
#pragma unroll
        for (int kk = 0; kk < 4; kk++) {
            b[kk * 2]     = *((float4*)&sW[(k + kk) * 128 + c0]);
            b[kk * 2 + 1] = *((float4*)&sW[(k + kk) * 128 + c0 + 4]);
        }
#pragma unroll
        for (int i = 0; i < 8; i++) {
            float av[4] = {a[i].x, a[i].y, a[i].z, a[i].w};
#pragma unroll
            for (int kk = 0; kk < 4; kk++) {
                float4 b0v = b[kk * 2], b1v = b[kk * 2 + 1];
                acc[i][0] += av[kk] * b0v.x;
                acc[i][1] += av[kk] * b0v.y;
                acc[i][2] += av[kk] * b0v.z;
                acc[i][3] += av[kk] * b0v.w;
                acc[i][4] += av[kk] * b1v.x;
                acc[i][5] += av[kk] * b1v.y;
                acc[i][6] += av[kk] * b1v.z;
                acc[i][7] += av[kk] * b1v.w;
            }
        }
    }
#pragma unroll
    for (int i = 0; i < 8; i++) {
        int gr = base + r0 + i;
        if (gr < n) {
            float4 v0 = make_float4(acc[i][0], acc[i][1], acc[i][2], acc[i][3]);
            float4 v1 = make_float4(acc[i][4], acc[i][5], acc[i][6], acc[i][7]);
            *((float4*)&C[(size_t)gr * DH + c0]) = v0;
            *((float4*)&C[(size_t)gr * DH + c0 + 4]) = v1;
        }
    }
}

// ---------------- pooling ----------------
__device__ inline int lbound(const int* a, int n, int v) {
    int lo = 0, hi = n;
    while (lo < hi) {
        int mid = (lo + hi) >> 1;
        if (a[mid] < v) lo = mid + 1; else hi = mid;
    }
    return lo;
}

__global__ __launch_bounds__(128) void k_pool(const float* __restrict__ H, const int* __restrict__ conn,
                                              const int* __restrict__ batch, float* sums, float* cntB, int n) {
    int b = blockIdx.x >> 3;
    int s = blockIdx.x & 7;
    int start = lbound(batch, n, b);
    int end = lbound(batch, n, b + 1);
    int d = threadIdx.x;
    float acc = 0.f, c = 0.f;
    for (int i = start + s; i < end; i += 8) {
        if (conn[i]) {
            acc += H[(size_t)i * DH + d];
            c += 1.f;
        }
    }
    atomicAdd(&sums[b * DH + d], acc);
    if (d == 0) atomicAdd(&cntB[b], c);
}

// ---------------- MLP head ----------------
__global__ __launch_bounds__(256) void k_mlp(const float* __restrict__ sums, const float* __restrict__ cntB,
                                             const float* __restrict__ M1, const float* __restrict__ mb1,
                                             const float* __restrict__ M2, const float* __restrict__ mb2,
                                             float* out) {
    int b = blockIdx.x;
    int j = threadIdx.x;
    __shared__ float g[DH];
    __shared__ float red[DMLP];
    float inv = 1.0f / fmaxf(cntB[b], 1.0f);
    if (j < DH) g[j] = sums[b * DH + j] * inv;
    __syncthreads();
    float acc = mb1[j];
    for (int k = 0; k < DH; k++) acc += g[k] * M1[k * DMLP + j];
    float v = fmaxf(acc, 0.f) * M2[j];
    red[j] = v;
    __syncthreads();
    for (int sdiv = 128; sdiv > 0; sdiv >>= 1) {
        if (j < sdiv) red[j] += red[j + sdiv];
        __syncthreads();
    }
    if (j == 0) out[b] = red[0] + mb2[0];
}

// ---------------- launch ----------------
extern "C" void kernel_launch(void* const* d_in, const int* in_sizes, int n_in,
                              void* d_out, int out_size, void* d_ws, size_t ws_size,
                              hipStream_t stream) {
    const int* x      = (const int*)d_in[0];
    const int* ei     = (const int*)d_in[1];
    const int* batch  = (const int*)d_in[2];
    const float* emb  = (const float*)d_in[3];
    const float* W0   = (const float*)d_in[4];
    const float* b0   = (const float*)d_in[5];
    const float* W1   = (const float*)d_in[6];
    const float* b1   = (const float*)d_in[7];
    const float* W2   = (const float*)d_in[8];
    const float* b2   = (const float*)d_in[9];
    const float* P0   = (const float*)d_in[10];
    const float* pb0  = (const float*)d_in[11];
    const float* M1   = (const float*)d_in[12];
    const float* mb1  = (const float*)d_in[13];
    const float* M2   = (const float*)d_in[14];
    const float* mb2  = (const float*)d_in[15];
    float* out = (float*)d_out;

    const int* row = ei;
    const int* col = ei + EE;

    char* p = (char*)d_ws;
    auto alloc = [&](size_t bytes) {
        void* q = (void*)p;
        p += (bytes + 255) & ~(size_t)255;
        return q;
    };
    int* cnt      = (int*)alloc(NN * 4);
    int* off      = (int*)alloc(NN * 4);
    int* cursor   = (int*)alloc(NN * 4);
    int* conn     = (int*)alloc(NN * 4);
    float* dinv   = (float*)alloc(NN * 4);
    int2* nodeP   = (int2*)alloc((size_t)NN * 8);
    int* total    = (int*)alloc(256);
    int2* edges   = (int2*)alloc((size_t)EDGE_CAP * 8);
    float* Tm     = (float*)alloc(TT * DH * 4);
    float* Tp     = (float*)alloc(TT * DH * 4);
    float* H      = (float*)alloc((size_t)NN * DH * 4);
    float* M      = (float*)alloc((size_t)NN * DH * 4);
    float* sums   = (float*)alloc(BB * DH * 4);
    float* cntB   = (float*)alloc(BB * 4);

    int gN = (NN + 255) / 256;
    int gE = (EE + 255) / 256;

    k_init<<<gN, 256, 0, stream>>>(cnt, conn, sums, cntB, total, NN);
    k_count<<<gE, 256, 0, stream>>>(row, col, cnt, conn, EE);
    k_alloc<<<gN, 256, 0, stream>>>(cnt, x, off, cursor, dinv, nodeP, edges, total, NN);
    k_fill<<<gE, 256, 0, stream>>>(row, col, cursor, edges, nodeP, EE);
    k_tables<<<TT, 128, 0, stream>>>(emb, W0, P0, pb0, Tm, Tp);
    k_agg0<<<(NN + 7) / 8, 256, 0, stream>>>(H, edges, off, cnt, dinv, b0, x, Tm, Tp, NN);
    k_gemm<<<(NN + 127) / 128, 256, 0, stream>>>(H, W1, M, NN);
    k_agg<1><<<(NN + 7) / 8, 256, 0, stream>>>(M, H, edges, off, cnt, dinv, b1, NN);
    k_gemm<<<(NN + 127) / 128, 256, 0, stream>>>(H, W2, M, NN);
    k_agg<0><<<(NN + 7) / 8, 256, 0, stream>>>(M, H, edges, off, cnt, dinv, b2, NN);
    k_pool<<<BB * 8, 128, 0, stream>>>(H, conn, batch, sums, cntB, NN);
    k_mlp<<<BB, 256, 0, stream>>>(sums, cntB, M1, mb1, M2, mb2, out);
}